// Round 7
// baseline (423.455 us; speedup 1.0000x reference)
//
#include <hip/hip_runtime.h>

#define NB 62
#define NC 5
#define KTOP 49

typedef unsigned short ushort_t;
typedef unsigned int uint_t;

__device__ __forceinline__ float sigmf(float x) {
    return 1.0f / (1.0f + __expf(-x));
}

__device__ __forceinline__ ushort_t f2b(float f) {   // f32 -> bf16 (RNE)
    union { float f; uint_t u; } cv; cv.f = f;
    uint_t r = (cv.u + 0x7fffu + ((cv.u >> 16) & 1u)) >> 16;
    return (ushort_t)r;
}
__device__ __forceinline__ float blo(uint_t w) {
    union { uint_t u; float f; } cv; cv.u = w << 16; return cv.f;
}
__device__ __forceinline__ float bhi(uint_t w) {
    union { uint_t u; float f; } cv; cv.u = w & 0xffff0000u; return cv.f;
}
__device__ __forceinline__ float bits2f(uint_t u) {
    union { uint_t u; float f; } cv; cv.u = u; return cv.f;
}

__device__ __forceinline__ float tmax62(const float* a) {
    float t0 = a[0], t1 = a[1], t2 = a[2], t3 = a[3];
    #pragma unroll
    for (int m = 4; m < 60; m += 4) {
        t0 = fmaxf(t0, a[m]);     t1 = fmaxf(t1, a[m + 1]);
        t2 = fmaxf(t2, a[m + 2]); t3 = fmaxf(t3, a[m + 3]);
    }
    t0 = fmaxf(t0, a[60]); t1 = fmaxf(t1, a[61]);
    return fmaxf(fmaxf(t0, t1), fmaxf(t2, t3));
}
__device__ __forceinline__ float tsum62(const float* a) {
    float t0 = a[0], t1 = a[1], t2 = a[2], t3 = a[3];
    #pragma unroll
    for (int m = 4; m < 60; m += 4) {
        t0 += a[m]; t1 += a[m + 1]; t2 += a[m + 2]; t3 += a[m + 3];
    }
    t0 += a[60]; t1 += a[61];
    return (t0 + t1) + (t2 + t3);
}

// ascending bitonic sort of 16 register-resident floats
__device__ __forceinline__ void sort16(float* s) {
    #pragma unroll
    for (int k = 2; k <= 16; k <<= 1) {
        #pragma unroll
        for (int j = k >> 1; j > 0; j >>= 1) {
            #pragma unroll
            for (int i = 0; i < 16; ++i) {
                const int p = i ^ j;
                if (p > i) {
                    const bool up = ((i & k) == 0);
                    const float a = s[i], c = s[p];
                    s[i] = up ? fminf(a, c) : fmaxf(a, c);
                    s[p] = up ? fmaxf(a, c) : fminf(a, c);
                }
            }
        }
    }
}
// m asc, b asc  ->  m = 16 smallest of the union, ascending
__device__ __forceinline__ void merge_low16(float* m, const float* b) {
    float t[16];
    #pragma unroll
    for (int i = 0; i < 16; ++i) t[i] = fminf(m[i], b[15 - i]);  // half-cleaner
    #pragma unroll
    for (int j = 8; j > 0; j >>= 1) {                            // bitonic merge
        #pragma unroll
        for (int i = 0; i < 16; ++i) {
            const int p = i ^ j;
            if (p > i) {
                const float a = t[i], c = t[p];
                t[i] = fminf(a, c);
                t[p] = fmaxf(a, c);
            }
        }
    }
    #pragma unroll
    for (int i = 0; i < 16; ++i) m[i] = t[i];
}

// Repack FC weights into d_ws: fc1w[64][930] -> bf16 [117][64][8] (zero-pad 936),
// fc2w[64][64] -> f32 [16][64][4]. Makes the FC loops fully coalesced.
__global__ void repack_kernel(const float* __restrict__ fc1w,
                              const float* __restrict__ fc2w,
                              ushort_t* __restrict__ w1o,
                              float* __restrict__ w2o) {
    const int i = blockIdx.x * 256 + threadIdx.x;
    if (i < 117 * 64 * 8) {
        const int j = i & 7, o = (i >> 3) & 63, i8 = i >> 9;
        const int src = i8 * 8 + j;
        const float v = (src < 930) ? fc1w[o * 930 + src] : 0.0f;
        w1o[i] = f2b(v);
    } else if (i < 117 * 64 * 8 + 16 * 64 * 4) {
        const int i2 = i - 117 * 64 * 8;
        const int j = i2 & 3, o = (i2 >> 2) & 63, k4 = i2 >> 8;
        w2o[i2] = fc2w[o * 64 + k4 * 4 + j];
    }
}

// One DGCN layer. L==0: input = global x[b] (re-read phase-locally, never live
// across the selection); output -> s_x1. L==1: input = s_x1; output -> f2out.
// mem is read directly from global (wave-uniform addresses -> scalar loads).
template <int L>
__device__ __forceinline__ void dgcn_layer(
    const int tid, const float* __restrict__ xin_g,
    const float* __restrict__ conv_w, const float* __restrict__ conv_b,
    const float* __restrict__ memp,
    const float* __restrict__ gfc_w, const float* __restrict__ gfc_b,
    const float* __restrict__ gcn_w, const float* __restrict__ gcn_b,
    float (*__restrict__ s_xc4)[4], float* __restrict__ s_xc1,
    uint_t* __restrict__ s_adj32,
    float (*__restrict__ s_x1)[NC], float* __restrict__ f2out)
{
    const float scale = 0.44721359549995793f; // 1/sqrt(5)

    float cw[25], cbv[5];
    #pragma unroll
    for (int i = 0; i < 25; ++i) cw[i] = conv_w[i];
    #pragma unroll
    for (int i = 0; i < 5; ++i)  cbv[i] = conv_b[i];
    const float w0 = gfc_w[0], w1 = gfc_w[1], b0 = gfc_b[0];

    // ---- conv1x1 on own node (input regs die before the selection) ----
    float xo0 = 0, xo1 = 0, xo2 = 0, xo3 = 0, xo4 = 0;
    if (tid < NB) {
        float xn[5];
        #pragma unroll
        for (int c = 0; c < 5; ++c)
            xn[c] = (L == 0) ? xin_g[c * NB + tid] : s_x1[tid][c];
        xo0 = cbv[0]; xo1 = cbv[1]; xo2 = cbv[2]; xo3 = cbv[3]; xo4 = cbv[4];
        #pragma unroll
        for (int c = 0; c < 5; ++c) {
            xo0 = fmaf(cw[c],      xn[c], xo0);
            xo1 = fmaf(cw[5 + c],  xn[c], xo1);
            xo2 = fmaf(cw[10 + c], xn[c], xo2);
            xo3 = fmaf(cw[15 + c], xn[c], xo3);
            xo4 = fmaf(cw[20 + c], xn[c], xo4);
        }
        s_xc4[tid][0] = xo0; s_xc4[tid][1] = xo1;
        s_xc4[tid][2] = xo2; s_xc4[tid][3] = xo3;
        s_xc1[tid] = xo4;
    }
    __syncthreads();

    // ---- row phase: thread n owns row n ----
    if (tid < NB) {
        float r1[NB];
        float r2[NB];
        #pragma unroll
        for (int m = 0; m < NB; ++m) {
            const float4 xc03 = *(const float4*)&s_xc4[m][0];
            const float  xc4  = s_xc1[m];
            // mem: wave-uniform global reads (scalar-cache resident, 1.2 KB)
            const float me0 = memp[0 * NB + m], me1 = memp[1 * NB + m];
            const float me2 = memp[2 * NB + m], me3 = memp[3 * NB + m];
            const float me4 = memp[4 * NB + m];
            float s1 = xo0 * me0 + xo1 * me1 + xo2 * me2 + xo3 * me3 + xo4 * me4;
            float s2 = xo0 * xc03.x + xo1 * xc03.y + xo2 * xc03.z + xo3 * xc03.w + xo4 * xc4;
            r1[m] = fmaxf(s1 * scale, 0.0f);
            r2[m] = fmaxf(s2 * scale, 0.0f);
        }
        const float mx1 = tmax62(r1);
        #pragma unroll
        for (int m = 0; m < NB; ++m) r1[m] = __expf(r1[m] - mx1);
        const float inv1 = 1.0f / tsum62(r1);
        const float mx2 = tmax62(r2);
        #pragma unroll
        for (int m = 0; m < NB; ++m) r2[m] = __expf(r2[m] - mx2);
        const float inv2 = 1.0f / tsum62(r2);
        #pragma unroll
        for (int m = 0; m < NB; ++m)
            r1[m] = b0 + (r1[m] * inv1) * w0 + (r2[m] * inv2) * w1;   // r2 dies
        const float mxa = tmax62(r1);
        #pragma unroll
        for (int m = 0; m < NB; ++m) r1[m] = __expf(r1[m] - mxa);
        const float inva = 1.0f / tsum62(r1);
        #pragma unroll
        for (int m = 0; m < NB; ++m) r1[m] *= inva;

        // ---- 49th-largest (=14th-smallest) via partial selection network:
        //      4x sort16 + 3x keep-lowest-16 merge. Same exact vth as a full
        //      sort; peak extra live regs 32 (vs 64). ----
        float ga[16], gb[16];
        #pragma unroll
        for (int i = 0; i < 16; ++i) ga[i] = r1[i];
        sort16(ga);
        #pragma unroll
        for (int i = 0; i < 16; ++i) gb[i] = r1[16 + i];
        sort16(gb);
        merge_low16(ga, gb);
        #pragma unroll
        for (int i = 0; i < 16; ++i) gb[i] = r1[32 + i];
        sort16(gb);
        merge_low16(ga, gb);
        #pragma unroll
        for (int i = 0; i < 14; ++i) gb[i] = r1[48 + i];
        gb[14] = INFINITY; gb[15] = INFINITY;
        sort16(gb);
        merge_low16(ga, gb);
        const float vth = ga[13];   // 14th smallest == 49th largest

        // ---- tie-aware selection == jax.lax.top_k (lower index first) ----
        int gc0 = 0, gc1 = 0, gc2 = 0, gc3 = 0;
        #pragma unroll
        for (int m = 0; m < 60; m += 4) {
            gc0 += (r1[m] > vth);     gc1 += (r1[m + 1] > vth);
            gc2 += (r1[m + 2] > vth); gc3 += (r1[m + 3] > vth);
        }
        gc0 += (r1[60] > vth); gc1 += (r1[61] > vth);
        const int G = (gc0 + gc1) + (gc2 + gc3);
        int eq = 0;
        uint_t pend = 0;
        #pragma unroll
        for (int m = 0; m < NB; ++m) {
            const bool e  = (r1[m] == vth);
            const bool ss = (r1[m] > vth) || (e && (G + eq) < KTOP);
            const uint_t h = (uint_t)f2b(ss ? r1[m] : 0.0f);
            if (m & 1) s_adj32[tid * 31 + (m >> 1)] = pend | (h << 16);
            else       pend = h;
            eq += e ? 1 : 0;
        }
    }
    __syncthreads();

    // ---- diffusion + gcn mix + skip: thread m computes output column m ----
    if (tid < NB) {
        const int m = tid;
        const int dw = m >> 1;
        const uint_t sh = (m & 1) ? 16u : 0u;
        float y0 = 0, y1 = 0, y2 = 0, y3 = 0, y4 = 0;
        for (int n = 0; n < NB; ++n) {
            // stride 31 dwords (odd): 62 lanes hit 31 consecutive dwords,
            // 2 lanes/dword same-address broadcast -> conflict-free
            const uint_t w = s_adj32[n * 31 + dw];
            const float a = bits2f((w >> sh) << 16);
            const float4 xv = *(const float4*)&s_xc4[n][0];
            const float  xv4 = s_xc1[n];
            y0 = fmaf(xv.x, a, y0); y1 = fmaf(xv.y, a, y1); y2 = fmaf(xv.z, a, y2);
            y3 = fmaf(xv.w, a, y3); y4 = fmaf(xv4, a, y4);
        }
        float gwv[25], gbv[5];
        #pragma unroll
        for (int i = 0; i < 25; ++i) gwv[i] = gcn_w[i];
        #pragma unroll
        for (int i = 0; i < 5; ++i)  gbv[i] = gcn_b[i];
        #pragma unroll
        for (int o = 0; o < 5; ++o) {
            const float z = gbv[o] + gwv[o * 5 + 0] * y0 + gwv[o * 5 + 1] * y1 +
                            gwv[o * 5 + 2] * y2 + gwv[o * 5 + 3] * y3 + gwv[o * 5 + 4] * y4;
            const float fi = (L == 0) ? xin_g[o * NB + m] : s_x1[m][o];
            const float zz = z + fi;
            if (L == 0) s_x1[m][o] = zz;
            else        f2out[o]   = zz;
        }
    }
    __syncthreads();
}

// waves_per_eu(4,4): pin allocation at 128 VGPRs (peak live ~125-135 after the
// partial-selection rewrite -> at most a handful of cache-resident spills).
// LDS 10168 B -> 16 blocks/CU (16 x 10240 = exactly 160 KB) = 4 waves/EU.
__global__ void __launch_bounds__(64) __attribute__((amdgpu_waves_per_eu(4, 4)))
encoder_kernel(
    const float* __restrict__ g_x,
    const float* __restrict__ c0w, const float* __restrict__ c0b,
    const float* __restrict__ m0,  const float* __restrict__ f0w,
    const float* __restrict__ f0b, const float* __restrict__ g0w,
    const float* __restrict__ g0b,
    const float* __restrict__ c1w, const float* __restrict__ c1b,
    const float* __restrict__ m1,  const float* __restrict__ f1w,
    const float* __restrict__ f1b, const float* __restrict__ g1w,
    const float* __restrict__ g1b,
    const float* __restrict__ caw1, const float* __restrict__ caw2,
    const float* __restrict__ saw,  const float* __restrict__ sab,
    const float* __restrict__ fc1w, const float* __restrict__ fc1b,
    const float* __restrict__ fc2w, const float* __restrict__ fc2b,
    const ushort_t* __restrict__ w1b, const float* __restrict__ w2p,
    const int use_ws,
    float* __restrict__ g_out)
{
    const int b   = blockIdx.x;
    const int tid = threadIdx.x;

    // LDS: 992 + 248 + 7688 + 1240 = 10168 B
    __shared__ __align__(16) float s_xc4[NB][4];
    __shared__ __align__(16) float s_xc1[NB];
    __shared__ __align__(16) uint_t s_adj32[NB * 31];
    __shared__ __align__(16) float s_x1[NB][NC];

    float* const s_g  = (float*)s_adj32;        // 936 f32 alias (adjacency dead)
    float* const s_h1 = ((float*)s_adj32) + 936;

    const float* xin = g_x + (size_t)b * (NC * NB);

    float f2[5] = {0, 0, 0, 0, 0};
    dgcn_layer<0>(tid, xin, c0w, c0b, m0, f0w, f0b, g0w, g0b,
                  s_xc4, s_xc1, s_adj32, s_x1, nullptr);
    dgcn_layer<1>(tid, xin, c1w, c1b, m1, f1w, f1b, g1w, g1b,
                  s_xc4, s_xc1, s_adj32, s_x1, f2);

    // ================= CBAM (shuffle-based, all post-selection) =================
    float f0[5], f1v[5];
    #pragma unroll
    for (int c = 0; c < 5; ++c) {
        f0[c]  = (tid < NB) ? xin[c * NB + tid] : 0.0f;
        f1v[c] = (tid < NB) ? s_x1[tid][c] : 0.0f;
    }

    float mxp[15], avp[15];
    #pragma unroll
    for (int c = 0; c < 15; ++c) {
        const float v = (c < 5) ? f0[c] : (c < 10) ? f1v[c - 5] : f2[c - 10];
        float vm = (tid < NB) ? v : -INFINITY;
        float vs = (tid < NB) ? v : 0.0f;
        #pragma unroll
        for (int off = 32; off > 0; off >>= 1) {
            vm = fmaxf(vm, __shfl_xor(vm, off, 64));
            vs += __shfl_xor(vs, off, 64);
        }
        mxp[c] = vm;
        avp[c] = vs * (1.0f / 62.0f);
    }
    float ca[15];
    {
        float hm[3], ha[3];
        #pragma unroll
        for (int o = 0; o < 3; ++o) {
            float am = 0.0f, aa = 0.0f;
            #pragma unroll
            for (int c = 0; c < 15; ++c) {
                const float w = caw1[o * 15 + c];
                am = fmaf(mxp[c], w, am);
                aa = fmaf(avp[c], w, aa);
            }
            hm[o] = fmaxf(am, 0.0f);
            ha[o] = fmaxf(aa, 0.0f);
        }
        #pragma unroll
        for (int c = 0; c < 15; ++c) {
            float t = 0.0f;
            #pragma unroll
            for (int o = 0; o < 3; ++o) t = fmaf(hm[o] + ha[o], caw2[c * 3 + o], t);
            ca[c] = sigmf(t);
        }
    }
    float og[15];
    float smx = -INFINITY, ssum = 0.0f;
    #pragma unroll
    for (int c = 0; c < 15; ++c) {
        const float fv = (c < 5) ? f0[c] : (c < 10) ? f1v[c - 5] : f2[c - 10];
        const float v = fv * ca[c];
        og[c] = v;
        smx = fmaxf(smx, v);
        ssum += v;
    }
    const float smean = ssum * (1.0f / 15.0f);
    const float sxl = __shfl_up(smx, 1, 64),   sml = __shfl_up(smean, 1, 64);
    const float sxr = __shfl_down(smx, 1, 64), smr = __shfl_down(smean, 1, 64);
    const float mskL = (tid > 0) ? 1.0f : 0.0f;
    const float mskR = (tid < NB - 1) ? 1.0f : 0.0f;
    float t = sab[0];
    t += mskL * (sxl * saw[1] + sml * saw[10]);
    t += smx * saw[4] + smean * saw[13];
    t += mskR * (sxr * saw[7] + smr * saw[16]);
    const float sa = sigmf(t);

    __syncthreads();  // adjacency dead; region becomes s_g/s_h1
    if (tid < NB) {
        #pragma unroll
        for (int c = 0; c < 15; ++c) {
            const float fv = (c < 5) ? f0[c] : (c < 10) ? f1v[c - 5] : f2[c - 10];
            s_g[c * NB + tid] = og[c] * sa + fv;
        }
    }
    if (tid < 6) s_g[930 + tid] = 0.0f;   // zero pad to 936
    __syncthreads();

    // ================= FC head =================
    if (use_ws) {
        float acc = fc1b[tid];
        const uint4* w1v = (const uint4*)w1b;
        #pragma unroll 4
        for (int i8 = 0; i8 < 117; ++i8) {
            const uint4 wv = w1v[i8 * 64 + tid];
            const float4 ga4 = *(const float4*)&s_g[i8 * 8];
            const float4 gb4 = *(const float4*)&s_g[i8 * 8 + 4];
            acc = fmaf(blo(wv.x), ga4.x, acc);
            acc = fmaf(bhi(wv.x), ga4.y, acc);
            acc = fmaf(blo(wv.y), ga4.z, acc);
            acc = fmaf(bhi(wv.y), ga4.w, acc);
            acc = fmaf(blo(wv.z), gb4.x, acc);
            acc = fmaf(bhi(wv.z), gb4.y, acc);
            acc = fmaf(blo(wv.w), gb4.z, acc);
            acc = fmaf(bhi(wv.w), gb4.w, acc);
        }
        s_h1[tid] = fmaxf(acc, 0.0f);
        __syncthreads();
        float acc2 = fc2b[tid];
        #pragma unroll
        for (int k4 = 0; k4 < 16; ++k4) {
            const float4 wv = *(const float4*)(w2p + k4 * 256 + tid * 4);
            const float4 hv = *(const float4*)&s_h1[k4 * 4];
            acc2 = fmaf(wv.x, hv.x, acc2);
            acc2 = fmaf(wv.y, hv.y, acc2);
            acc2 = fmaf(wv.z, hv.z, acc2);
            acc2 = fmaf(wv.w, hv.w, acc2);
        }
        g_out[(size_t)b * 64 + tid] = fmaxf(acc2, 0.0f);
    } else {
        float acc = fc1b[tid];
        const float* wr = fc1w + (size_t)tid * 930;
        #pragma unroll 4
        for (int i = 0; i < 928; i += 2) {
            const float2 wv = *(const float2*)(wr + i);
            const float2 gv = *(const float2*)(&s_g[i]);
            acc = fmaf(wv.x, gv.x, fmaf(wv.y, gv.y, acc));
        }
        acc += wr[928] * s_g[928] + wr[929] * s_g[929];
        s_h1[tid] = fmaxf(acc, 0.0f);
        __syncthreads();
        float acc2 = fc2b[tid];
        const float* wr2 = fc2w + tid * 64;
        #pragma unroll
        for (int k = 0; k < 64; k += 4) {
            const float4 wv = *(const float4*)(wr2 + k);
            acc2 = fmaf(wv.x, s_h1[k], acc2);
            acc2 = fmaf(wv.y, s_h1[k + 1], acc2);
            acc2 = fmaf(wv.z, s_h1[k + 2], acc2);
            acc2 = fmaf(wv.w, s_h1[k + 3], acc2);
        }
        g_out[(size_t)b * 64 + tid] = fmaxf(acc2, 0.0f);
    }
}

extern "C" void kernel_launch(void* const* d_in, const int* in_sizes, int n_in,
                              void* d_out, int out_size, void* d_ws, size_t ws_size,
                              hipStream_t stream) {
    const float* X    = (const float*)d_in[0];
    const float* C0W  = (const float*)d_in[1];
    const float* C0B  = (const float*)d_in[2];
    const float* M0   = (const float*)d_in[3];
    const float* F0W  = (const float*)d_in[4];
    const float* F0B  = (const float*)d_in[5];
    const float* G0W  = (const float*)d_in[6];
    const float* G0B  = (const float*)d_in[7];
    const float* C1W  = (const float*)d_in[8];
    const float* C1B  = (const float*)d_in[9];
    const float* M1   = (const float*)d_in[10];
    const float* F1W  = (const float*)d_in[11];
    const float* F1B  = (const float*)d_in[12];
    const float* G1W  = (const float*)d_in[13];
    const float* G1B  = (const float*)d_in[14];
    const float* CAW1 = (const float*)d_in[15];
    const float* CAW2 = (const float*)d_in[16];
    const float* SAW  = (const float*)d_in[17];
    const float* SAB  = (const float*)d_in[18];
    const float* FC1W = (const float*)d_in[19];
    const float* FC1B = (const float*)d_in[20];
    const float* FC2W = (const float*)d_in[21];
    const float* FC2B = (const float*)d_in[22];

    const int B = in_sizes[0] / (NC * NB);

    const size_t W1_BYTES = 117 * 64 * 8 * sizeof(ushort_t); // 119808
    const size_t W2_BYTES = 16 * 64 * 4 * sizeof(float);     // 16384
    const int use_ws = (ws_size >= W1_BYTES + W2_BYTES) ? 1 : 0;
    ushort_t* w1b = (ushort_t*)d_ws;
    float*    w2p = (float*)((char*)d_ws + W1_BYTES);

    if (use_ws) {
        repack_kernel<<<250, 256, 0, stream>>>(FC1W, FC2W, w1b, w2p);
    }

    encoder_kernel<<<B, 64, 0, stream>>>(
        X, C0W, C0B, M0, F0W, F0B, G0W, G0B,
        C1W, C1B, M1, F1W, F1B, G1W, G1B,
        CAW1, CAW2, SAW, SAB, FC1W, FC1B, FC2W, FC2B,
        w1b, w2p, use_ws,
        (float*)d_out);
}

// Round 8
// 271.237 us; speedup vs baseline: 1.5612x; 1.5612x over previous
//
#include <hip/hip_runtime.h>

#define NB 62
#define NC 5
#define KTOP 49

typedef unsigned short ushort_t;
typedef unsigned int uint_t;

__device__ __forceinline__ float sigmf(float x) {
    return 1.0f / (1.0f + __expf(-x));
}

__device__ __forceinline__ ushort_t f2b(float f) {   // f32 -> bf16 (RNE)
    union { float f; uint_t u; } cv; cv.f = f;
    uint_t r = (cv.u + 0x7fffu + ((cv.u >> 16) & 1u)) >> 16;
    return (ushort_t)r;
}
__device__ __forceinline__ float blo(uint_t w) {
    union { uint_t u; float f; } cv; cv.u = w << 16; return cv.f;
}
__device__ __forceinline__ float bhi(uint_t w) {
    union { uint_t u; float f; } cv; cv.u = w & 0xffff0000u; return cv.f;
}
__device__ __forceinline__ float bits2f(uint_t u) {
    union { uint_t u; float f; } cv; cv.u = u; return cv.f;
}

__device__ __forceinline__ float tmax62(const float* a) {
    float t0 = a[0], t1 = a[1], t2 = a[2], t3 = a[3];
    #pragma unroll
    for (int m = 4; m < 60; m += 4) {
        t0 = fmaxf(t0, a[m]);     t1 = fmaxf(t1, a[m + 1]);
        t2 = fmaxf(t2, a[m + 2]); t3 = fmaxf(t3, a[m + 3]);
    }
    t0 = fmaxf(t0, a[60]); t1 = fmaxf(t1, a[61]);
    return fmaxf(fmaxf(t0, t1), fmaxf(t2, t3));
}
__device__ __forceinline__ float tsum62(const float* a) {
    float t0 = a[0], t1 = a[1], t2 = a[2], t3 = a[3];
    #pragma unroll
    for (int m = 4; m < 60; m += 4) {
        t0 += a[m]; t1 += a[m + 1]; t2 += a[m + 2]; t3 += a[m + 3];
    }
    t0 += a[60]; t1 += a[61];
    return (t0 + t1) + (t2 + t3);
}

// ascending bitonic sort of 16 register-resident floats
__device__ __forceinline__ void sort16(float* s) {
    #pragma unroll
    for (int k = 2; k <= 16; k <<= 1) {
        #pragma unroll
        for (int j = k >> 1; j > 0; j >>= 1) {
            #pragma unroll
            for (int i = 0; i < 16; ++i) {
                const int p = i ^ j;
                if (p > i) {
                    const bool up = ((i & k) == 0);
                    const float a = s[i], c = s[p];
                    s[i] = up ? fminf(a, c) : fmaxf(a, c);
                    s[p] = up ? fmaxf(a, c) : fminf(a, c);
                }
            }
        }
    }
}
// m asc, b asc  ->  m = 16 smallest of the union, ascending
__device__ __forceinline__ void merge_low16(float* m, const float* b) {
    float t[16];
    #pragma unroll
    for (int i = 0; i < 16; ++i) t[i] = fminf(m[i], b[15 - i]);  // half-cleaner
    #pragma unroll
    for (int j = 8; j > 0; j >>= 1) {                            // bitonic merge
        #pragma unroll
        for (int i = 0; i < 16; ++i) {
            const int p = i ^ j;
            if (p > i) {
                const float a = t[i], c = t[p];
                t[i] = fminf(a, c);
                t[p] = fmaxf(a, c);
            }
        }
    }
    #pragma unroll
    for (int i = 0; i < 16; ++i) m[i] = t[i];
}

// Repack FC weights into d_ws: fc1w[64][930] -> bf16 [117][64][8] (zero-pad 936),
// fc2w[64][64] -> f32 [16][64][4]. Makes the FC loops fully coalesced.
__global__ void repack_kernel(const float* __restrict__ fc1w,
                              const float* __restrict__ fc2w,
                              ushort_t* __restrict__ w1o,
                              float* __restrict__ w2o) {
    const int i = blockIdx.x * 256 + threadIdx.x;
    if (i < 117 * 64 * 8) {
        const int j = i & 7, o = (i >> 3) & 63, i8 = i >> 9;
        const int src = i8 * 8 + j;
        const float v = (src < 930) ? fc1w[o * 930 + src] : 0.0f;
        w1o[i] = f2b(v);
    } else if (i < 117 * 64 * 8 + 16 * 64 * 4) {
        const int i2 = i - 117 * 64 * 8;
        const int j = i2 & 3, o = (i2 >> 2) & 63, k4 = i2 >> 8;
        w2o[i2] = fc2w[o * 64 + k4 * 4 + j];
    }
}

// One DGCN layer. L==0: input = global x[b] (re-read phase-locally, never live
// across the selection); output -> s_x1. L==1: input = s_x1; output -> f2out.
// mem is read directly from global (wave-uniform addresses -> scalar loads).
template <int L>
__device__ __forceinline__ void dgcn_layer(
    const int tid, const float* __restrict__ xin_g,
    const float* __restrict__ conv_w, const float* __restrict__ conv_b,
    const float* __restrict__ memp,
    const float* __restrict__ gfc_w, const float* __restrict__ gfc_b,
    const float* __restrict__ gcn_w, const float* __restrict__ gcn_b,
    float (*__restrict__ s_xc4)[4], float* __restrict__ s_xc1,
    uint_t* __restrict__ s_adj32,
    float (*__restrict__ s_x1)[NC], float* __restrict__ f2out)
{
    const float scale = 0.44721359549995793f; // 1/sqrt(5)

    float cw[25], cbv[5];
    #pragma unroll
    for (int i = 0; i < 25; ++i) cw[i] = conv_w[i];
    #pragma unroll
    for (int i = 0; i < 5; ++i)  cbv[i] = conv_b[i];
    const float w0 = gfc_w[0], w1 = gfc_w[1], b0 = gfc_b[0];

    // ---- conv1x1 on own node (input regs die before the selection) ----
    float xo0 = 0, xo1 = 0, xo2 = 0, xo3 = 0, xo4 = 0;
    if (tid < NB) {
        float xn[5];
        #pragma unroll
        for (int c = 0; c < 5; ++c)
            xn[c] = (L == 0) ? xin_g[c * NB + tid] : s_x1[tid][c];
        xo0 = cbv[0]; xo1 = cbv[1]; xo2 = cbv[2]; xo3 = cbv[3]; xo4 = cbv[4];
        #pragma unroll
        for (int c = 0; c < 5; ++c) {
            xo0 = fmaf(cw[c],      xn[c], xo0);
            xo1 = fmaf(cw[5 + c],  xn[c], xo1);
            xo2 = fmaf(cw[10 + c], xn[c], xo2);
            xo3 = fmaf(cw[15 + c], xn[c], xo3);
            xo4 = fmaf(cw[20 + c], xn[c], xo4);
        }
        s_xc4[tid][0] = xo0; s_xc4[tid][1] = xo1;
        s_xc4[tid][2] = xo2; s_xc4[tid][3] = xo3;
        s_xc1[tid] = xo4;
    }
    __syncthreads();

    // ---- row phase: thread n owns row n ----
    if (tid < NB) {
        float r1[NB];
        float r2[NB];
        #pragma unroll
        for (int m = 0; m < NB; ++m) {
            const float4 xc03 = *(const float4*)&s_xc4[m][0];
            const float  xc4  = s_xc1[m];
            // mem: wave-uniform global reads (scalar-cache resident, 1.2 KB)
            const float me0 = memp[0 * NB + m], me1 = memp[1 * NB + m];
            const float me2 = memp[2 * NB + m], me3 = memp[3 * NB + m];
            const float me4 = memp[4 * NB + m];
            float s1 = xo0 * me0 + xo1 * me1 + xo2 * me2 + xo3 * me3 + xo4 * me4;
            float s2 = xo0 * xc03.x + xo1 * xc03.y + xo2 * xc03.z + xo3 * xc03.w + xo4 * xc4;
            r1[m] = fmaxf(s1 * scale, 0.0f);
            r2[m] = fmaxf(s2 * scale, 0.0f);
        }
        const float mx1 = tmax62(r1);
        #pragma unroll
        for (int m = 0; m < NB; ++m) r1[m] = __expf(r1[m] - mx1);
        const float inv1 = 1.0f / tsum62(r1);
        const float mx2 = tmax62(r2);
        #pragma unroll
        for (int m = 0; m < NB; ++m) r2[m] = __expf(r2[m] - mx2);
        const float inv2 = 1.0f / tsum62(r2);
        #pragma unroll
        for (int m = 0; m < NB; ++m)
            r1[m] = b0 + (r1[m] * inv1) * w0 + (r2[m] * inv2) * w1;   // r2 dies
        const float mxa = tmax62(r1);
        #pragma unroll
        for (int m = 0; m < NB; ++m) r1[m] = __expf(r1[m] - mxa);
        const float inva = 1.0f / tsum62(r1);
        #pragma unroll
        for (int m = 0; m < NB; ++m) r1[m] *= inva;

        // ---- 49th-largest (=14th-smallest) via partial selection network:
        //      4x sort16 + 3x keep-lowest-16 merge. Same exact vth as a full
        //      sort; peak extra live regs 32 (vs 64). ----
        float ga[16], gb[16];
        #pragma unroll
        for (int i = 0; i < 16; ++i) ga[i] = r1[i];
        sort16(ga);
        #pragma unroll
        for (int i = 0; i < 16; ++i) gb[i] = r1[16 + i];
        sort16(gb);
        merge_low16(ga, gb);
        #pragma unroll
        for (int i = 0; i < 16; ++i) gb[i] = r1[32 + i];
        sort16(gb);
        merge_low16(ga, gb);
        #pragma unroll
        for (int i = 0; i < 14; ++i) gb[i] = r1[48 + i];
        gb[14] = INFINITY; gb[15] = INFINITY;
        sort16(gb);
        merge_low16(ga, gb);
        const float vth = ga[13];   // 14th smallest == 49th largest

        // ---- tie-aware selection == jax.lax.top_k (lower index first) ----
        int gc0 = 0, gc1 = 0, gc2 = 0, gc3 = 0;
        #pragma unroll
        for (int m = 0; m < 60; m += 4) {
            gc0 += (r1[m] > vth);     gc1 += (r1[m + 1] > vth);
            gc2 += (r1[m + 2] > vth); gc3 += (r1[m + 3] > vth);
        }
        gc0 += (r1[60] > vth); gc1 += (r1[61] > vth);
        const int G = (gc0 + gc1) + (gc2 + gc3);
        int eq = 0;
        uint_t pend = 0;
        #pragma unroll
        for (int m = 0; m < NB; ++m) {
            const bool e  = (r1[m] == vth);
            const bool ss = (r1[m] > vth) || (e && (G + eq) < KTOP);
            const uint_t h = (uint_t)f2b(ss ? r1[m] : 0.0f);
            if (m & 1) s_adj32[tid * 31 + (m >> 1)] = pend | (h << 16);
            else       pend = h;
            eq += e ? 1 : 0;
        }
    }
    __syncthreads();

    // ---- diffusion + gcn mix + skip: thread m computes output column m ----
    if (tid < NB) {
        const int m = tid;
        const int dw = m >> 1;
        const uint_t sh = (m & 1) ? 16u : 0u;
        float y0 = 0, y1 = 0, y2 = 0, y3 = 0, y4 = 0;
        for (int n = 0; n < NB; ++n) {
            // stride 31 dwords (odd): 62 lanes hit 31 consecutive dwords,
            // 2 lanes/dword same-address broadcast -> conflict-free
            const uint_t w = s_adj32[n * 31 + dw];
            const float a = bits2f((w >> sh) << 16);
            const float4 xv = *(const float4*)&s_xc4[n][0];
            const float  xv4 = s_xc1[n];
            y0 = fmaf(xv.x, a, y0); y1 = fmaf(xv.y, a, y1); y2 = fmaf(xv.z, a, y2);
            y3 = fmaf(xv.w, a, y3); y4 = fmaf(xv4, a, y4);
        }
        float gwv[25], gbv[5];
        #pragma unroll
        for (int i = 0; i < 25; ++i) gwv[i] = gcn_w[i];
        #pragma unroll
        for (int i = 0; i < 5; ++i)  gbv[i] = gcn_b[i];
        #pragma unroll
        for (int o = 0; o < 5; ++o) {
            const float z = gbv[o] + gwv[o * 5 + 0] * y0 + gwv[o * 5 + 1] * y1 +
                            gwv[o * 5 + 2] * y2 + gwv[o * 5 + 3] * y3 + gwv[o * 5 + 4] * y4;
            const float fi = (L == 0) ? xin_g[o * NB + m] : s_x1[m][o];
            const float zz = z + fi;
            if (L == 0) s_x1[m][o] = zz;
            else        f2out[o]   = zz;
        }
    }
    __syncthreads();
}

// waves_per_eu(2,3): the proven-safe budget (round 4/6). Round 7's (4,4) pin
// drove the allocator to 64 VGPRs -> ~50 spilled regs -> 0.5 GB/dispatch HBM
// scratch writeback. The max arg does NOT act as a register floor; only the
// min arg's ceiling (512/2=256) is reliable. With the partial-selection
// network the peak live set is ~115, so worst case is a small L2-resident
// spill set (round-6 behavior). LDS 10168 B -> 16 blocks/CU (LDS-capped).
__global__ void __launch_bounds__(64) __attribute__((amdgpu_waves_per_eu(2, 3)))
encoder_kernel(
    const float* __restrict__ g_x,
    const float* __restrict__ c0w, const float* __restrict__ c0b,
    const float* __restrict__ m0,  const float* __restrict__ f0w,
    const float* __restrict__ f0b, const float* __restrict__ g0w,
    const float* __restrict__ g0b,
    const float* __restrict__ c1w, const float* __restrict__ c1b,
    const float* __restrict__ m1,  const float* __restrict__ f1w,
    const float* __restrict__ f1b, const float* __restrict__ g1w,
    const float* __restrict__ g1b,
    const float* __restrict__ caw1, const float* __restrict__ caw2,
    const float* __restrict__ saw,  const float* __restrict__ sab,
    const float* __restrict__ fc1w, const float* __restrict__ fc1b,
    const float* __restrict__ fc2w, const float* __restrict__ fc2b,
    const ushort_t* __restrict__ w1b, const float* __restrict__ w2p,
    const int use_ws,
    float* __restrict__ g_out)
{
    const int b   = blockIdx.x;
    const int tid = threadIdx.x;

    // LDS: 992 + 248 + 7688 + 1240 = 10168 B
    __shared__ __align__(16) float s_xc4[NB][4];
    __shared__ __align__(16) float s_xc1[NB];
    __shared__ __align__(16) uint_t s_adj32[NB * 31];
    __shared__ __align__(16) float s_x1[NB][NC];

    float* const s_g  = (float*)s_adj32;        // 936 f32 alias (adjacency dead)
    float* const s_h1 = ((float*)s_adj32) + 936;

    const float* xin = g_x + (size_t)b * (NC * NB);

    float f2[5] = {0, 0, 0, 0, 0};
    dgcn_layer<0>(tid, xin, c0w, c0b, m0, f0w, f0b, g0w, g0b,
                  s_xc4, s_xc1, s_adj32, s_x1, nullptr);
    dgcn_layer<1>(tid, xin, c1w, c1b, m1, f1w, f1b, g1w, g1b,
                  s_xc4, s_xc1, s_adj32, s_x1, f2);

    // ================= CBAM (shuffle-based, all post-selection) =================
    float f0[5], f1v[5];
    #pragma unroll
    for (int c = 0; c < 5; ++c) {
        f0[c]  = (tid < NB) ? xin[c * NB + tid] : 0.0f;
        f1v[c] = (tid < NB) ? s_x1[tid][c] : 0.0f;
    }

    float mxp[15], avp[15];
    #pragma unroll
    for (int c = 0; c < 15; ++c) {
        const float v = (c < 5) ? f0[c] : (c < 10) ? f1v[c - 5] : f2[c - 10];
        float vm = (tid < NB) ? v : -INFINITY;
        float vs = (tid < NB) ? v : 0.0f;
        #pragma unroll
        for (int off = 32; off > 0; off >>= 1) {
            vm = fmaxf(vm, __shfl_xor(vm, off, 64));
            vs += __shfl_xor(vs, off, 64);
        }
        mxp[c] = vm;
        avp[c] = vs * (1.0f / 62.0f);
    }
    float ca[15];
    {
        float hm[3], ha[3];
        #pragma unroll
        for (int o = 0; o < 3; ++o) {
            float am = 0.0f, aa = 0.0f;
            #pragma unroll
            for (int c = 0; c < 15; ++c) {
                const float w = caw1[o * 15 + c];
                am = fmaf(mxp[c], w, am);
                aa = fmaf(avp[c], w, aa);
            }
            hm[o] = fmaxf(am, 0.0f);
            ha[o] = fmaxf(aa, 0.0f);
        }
        #pragma unroll
        for (int c = 0; c < 15; ++c) {
            float t = 0.0f;
            #pragma unroll
            for (int o = 0; o < 3; ++o) t = fmaf(hm[o] + ha[o], caw2[c * 3 + o], t);
            ca[c] = sigmf(t);
        }
    }
    float og[15];
    float smx = -INFINITY, ssum = 0.0f;
    #pragma unroll
    for (int c = 0; c < 15; ++c) {
        const float fv = (c < 5) ? f0[c] : (c < 10) ? f1v[c - 5] : f2[c - 10];
        const float v = fv * ca[c];
        og[c] = v;
        smx = fmaxf(smx, v);
        ssum += v;
    }
    const float smean = ssum * (1.0f / 15.0f);
    const float sxl = __shfl_up(smx, 1, 64),   sml = __shfl_up(smean, 1, 64);
    const float sxr = __shfl_down(smx, 1, 64), smr = __shfl_down(smean, 1, 64);
    const float mskL = (tid > 0) ? 1.0f : 0.0f;
    const float mskR = (tid < NB - 1) ? 1.0f : 0.0f;
    float t = sab[0];
    t += mskL * (sxl * saw[1] + sml * saw[10]);
    t += smx * saw[4] + smean * saw[13];
    t += mskR * (sxr * saw[7] + smr * saw[16]);
    const float sa = sigmf(t);

    __syncthreads();  // adjacency dead; region becomes s_g/s_h1
    if (tid < NB) {
        #pragma unroll
        for (int c = 0; c < 15; ++c) {
            const float fv = (c < 5) ? f0[c] : (c < 10) ? f1v[c - 5] : f2[c - 10];
            s_g[c * NB + tid] = og[c] * sa + fv;
        }
    }
    if (tid < 6) s_g[930 + tid] = 0.0f;   // zero pad to 936
    __syncthreads();

    // ================= FC head =================
    if (use_ws) {
        float acc = fc1b[tid];
        const uint4* w1v = (const uint4*)w1b;
        #pragma unroll 4
        for (int i8 = 0; i8 < 117; ++i8) {
            const uint4 wv = w1v[i8 * 64 + tid];
            const float4 ga4 = *(const float4*)&s_g[i8 * 8];
            const float4 gb4 = *(const float4*)&s_g[i8 * 8 + 4];
            acc = fmaf(blo(wv.x), ga4.x, acc);
            acc = fmaf(bhi(wv.x), ga4.y, acc);
            acc = fmaf(blo(wv.y), ga4.z, acc);
            acc = fmaf(bhi(wv.y), ga4.w, acc);
            acc = fmaf(blo(wv.z), gb4.x, acc);
            acc = fmaf(bhi(wv.z), gb4.y, acc);
            acc = fmaf(blo(wv.w), gb4.z, acc);
            acc = fmaf(bhi(wv.w), gb4.w, acc);
        }
        s_h1[tid] = fmaxf(acc, 0.0f);
        __syncthreads();
        float acc2 = fc2b[tid];
        #pragma unroll
        for (int k4 = 0; k4 < 16; ++k4) {
            const float4 wv = *(const float4*)(w2p + k4 * 256 + tid * 4);
            const float4 hv = *(const float4*)&s_h1[k4 * 4];
            acc2 = fmaf(wv.x, hv.x, acc2);
            acc2 = fmaf(wv.y, hv.y, acc2);
            acc2 = fmaf(wv.z, hv.z, acc2);
            acc2 = fmaf(wv.w, hv.w, acc2);
        }
        g_out[(size_t)b * 64 + tid] = fmaxf(acc2, 0.0f);
    } else {
        float acc = fc1b[tid];
        const float* wr = fc1w + (size_t)tid * 930;
        #pragma unroll 4
        for (int i = 0; i < 928; i += 2) {
            const float2 wv = *(const float2*)(wr + i);
            const float2 gv = *(const float2*)(&s_g[i]);
            acc = fmaf(wv.x, gv.x, fmaf(wv.y, gv.y, acc));
        }
        acc += wr[928] * s_g[928] + wr[929] * s_g[929];
        s_h1[tid] = fmaxf(acc, 0.0f);
        __syncthreads();
        float acc2 = fc2b[tid];
        const float* wr2 = fc2w + tid * 64;
        #pragma unroll
        for (int k = 0; k < 64; k += 4) {
            const float4 wv = *(const float4*)(wr2 + k);
            acc2 = fmaf(wv.x, s_h1[k], acc2);
            acc2 = fmaf(wv.y, s_h1[k + 1], acc2);
            acc2 = fmaf(wv.z, s_h1[k + 2], acc2);
            acc2 = fmaf(wv.w, s_h1[k + 3], acc2);
        }
        g_out[(size_t)b * 64 + tid] = fmaxf(acc2, 0.0f);
    }
}

extern "C" void kernel_launch(void* const* d_in, const int* in_sizes, int n_in,
                              void* d_out, int out_size, void* d_ws, size_t ws_size,
                              hipStream_t stream) {
    const float* X    = (const float*)d_in[0];
    const float* C0W  = (const float*)d_in[1];
    const float* C0B  = (const float*)d_in[2];
    const float* M0   = (const float*)d_in[3];
    const float* F0W  = (const float*)d_in[4];
    const float* F0B  = (const float*)d_in[5];
    const float* G0W  = (const float*)d_in[6];
    const float* G0B  = (const float*)d_in[7];
    const float* C1W  = (const float*)d_in[8];
    const float* C1B  = (const float*)d_in[9];
    const float* M1   = (const float*)d_in[10];
    const float* F1W  = (const float*)d_in[11];
    const float* F1B  = (const float*)d_in[12];
    const float* G1W  = (const float*)d_in[13];
    const float* G1B  = (const float*)d_in[14];
    const float* CAW1 = (const float*)d_in[15];
    const float* CAW2 = (const float*)d_in[16];
    const float* SAW  = (const float*)d_in[17];
    const float* SAB  = (const float*)d_in[18];
    const float* FC1W = (const float*)d_in[19];
    const float* FC1B = (const float*)d_in[20];
    const float* FC2W = (const float*)d_in[21];
    const float* FC2B = (const float*)d_in[22];

    const int B = in_sizes[0] / (NC * NB);

    const size_t W1_BYTES = 117 * 64 * 8 * sizeof(ushort_t); // 119808
    const size_t W2_BYTES = 16 * 64 * 4 * sizeof(float);     // 16384
    const int use_ws = (ws_size >= W1_BYTES + W2_BYTES) ? 1 : 0;
    ushort_t* w1b = (ushort_t*)d_ws;
    float*    w2p = (float*)((char*)d_ws + W1_BYTES);

    if (use_ws) {
        repack_kernel<<<250, 256, 0, stream>>>(FC1W, FC2W, w1b, w2p);
    }

    encoder_kernel<<<B, 64, 0, stream>>>(
        X, C0W, C0B, M0, F0W, F0B, G0W, G0B,
        C1W, C1B, M1, F1W, F1B, G1W, G1B,
        CAW1, CAW2, SAW, SAB, FC1W, FC1B, FC2W, FC2B,
        w1b, w2p, use_ws,
        (float*)d_out);
}

// Round 9
// 244.421 us; speedup vs baseline: 1.7325x; 1.1097x over previous
//
#include <hip/hip_runtime.h>

#define NB 62
#define NC 5
#define KTOP 49

typedef unsigned short ushort_t;
typedef unsigned int uint_t;

__device__ __forceinline__ float sigmf(float x) {
    return 1.0f / (1.0f + __expf(-x));
}

__device__ __forceinline__ ushort_t f2b(float f) {   // f32 -> bf16 (RNE)
    union { float f; uint_t u; } cv; cv.f = f;
    uint_t r = (cv.u + 0x7fffu + ((cv.u >> 16) & 1u)) >> 16;
    return (ushort_t)r;
}
__device__ __forceinline__ float blo(uint_t w) {
    union { uint_t u; float f; } cv; cv.u = w << 16; return cv.f;
}
__device__ __forceinline__ float bhi(uint_t w) {
    union { uint_t u; float f; } cv; cv.u = w & 0xffff0000u; return cv.f;
}
__device__ __forceinline__ float bits2f(uint_t u) {
    union { uint_t u; float f; } cv; cv.u = u; return cv.f;
}

__device__ __forceinline__ float tmax31(const float* a) {
    float t0 = a[0], t1 = a[1], t2 = a[2], t3 = a[3];
    #pragma unroll
    for (int m = 4; m < 28; m += 4) {
        t0 = fmaxf(t0, a[m]);     t1 = fmaxf(t1, a[m + 1]);
        t2 = fmaxf(t2, a[m + 2]); t3 = fmaxf(t3, a[m + 3]);
    }
    t0 = fmaxf(t0, a[28]); t1 = fmaxf(t1, a[29]); t2 = fmaxf(t2, a[30]);
    return fmaxf(fmaxf(t0, t1), fmaxf(t2, t3));
}
__device__ __forceinline__ float tsum31(const float* a) {
    float t0 = a[0], t1 = a[1], t2 = a[2], t3 = a[3];
    #pragma unroll
    for (int m = 4; m < 28; m += 4) {
        t0 += a[m]; t1 += a[m + 1]; t2 += a[m + 2]; t3 += a[m + 3];
    }
    t0 += a[28]; t1 += a[29]; t2 += a[30];
    return (t0 + t1) + (t2 + t3);
}

// ascending bitonic sort of 16 register-resident floats
__device__ __forceinline__ void sort16(float* s) {
    #pragma unroll
    for (int k = 2; k <= 16; k <<= 1) {
        #pragma unroll
        for (int j = k >> 1; j > 0; j >>= 1) {
            #pragma unroll
            for (int i = 0; i < 16; ++i) {
                const int p = i ^ j;
                if (p > i) {
                    const bool up = ((i & k) == 0);
                    const float a = s[i], c = s[p];
                    s[i] = up ? fminf(a, c) : fmaxf(a, c);
                    s[p] = up ? fmaxf(a, c) : fminf(a, c);
                }
            }
        }
    }
}
// m asc, b asc -> m = 16 smallest of union, ascending
__device__ __forceinline__ void merge_low16(float* m, const float* b) {
    float t[16];
    #pragma unroll
    for (int i = 0; i < 16; ++i) t[i] = fminf(m[i], b[15 - i]);
    #pragma unroll
    for (int j = 8; j > 0; j >>= 1) {
        #pragma unroll
        for (int i = 0; i < 16; ++i) {
            const int p = i ^ j;
            if (p > i) {
                const float a = t[i], c = t[p];
                t[i] = fminf(a, c);
                t[p] = fmaxf(a, c);
            }
        }
    }
    #pragma unroll
    for (int i = 0; i < 16; ++i) m[i] = t[i];
}

// Repack for pair layout: fc1w[64][930] -> bf16 [59][128][8] where
// [j][t][e] = fc1w[t>>1][ ((t&1)*59 + j)*8 + e ] (zero-pad past 929).
// fc2w[64][64] -> f32 [8][128][4]: [j][t][e] = fc2w[t>>1][(t&1)*32 + j*4 + e].
__global__ void repack_kernel(const float* __restrict__ fc1w,
                              const float* __restrict__ fc2w,
                              ushort_t* __restrict__ w1o,
                              float* __restrict__ w2o) {
    const int i = blockIdx.x * 256 + threadIdx.x;
    if (i < 59 * 128 * 8) {
        const int e = i & 7, t = (i >> 3) & 127, j = i >> 10;
        const int o = t >> 1, h = t & 1;
        const int f = (h * 59 + j) * 8 + e;
        const float v = (f < 930) ? fc1w[o * 930 + f] : 0.0f;
        w1o[i] = f2b(v);
    } else if (i < 59 * 128 * 8 + 8 * 128 * 4) {
        const int i2 = i - 59 * 128 * 8;
        const int e = i2 & 3, t = (i2 >> 2) & 127, j = i2 >> 9;
        const int o = t >> 1, h = t & 1;
        w2o[i2] = fc2w[o * 64 + h * 32 + j * 4 + e];
    }
}

// One DGCN layer, pair-split rows. L==0: input xin_g (global); out -> s_xout.
// L==1: input s_xin; out -> s_xout.
template <int L>
__device__ __forceinline__ void dgcn_layer(
    const int tid, const float* __restrict__ xin_g,
    const float* __restrict__ conv_w, const float* __restrict__ conv_b,
    const float* __restrict__ memp,
    const float* __restrict__ gfc_w, const float* __restrict__ gfc_b,
    const float* __restrict__ gcn_w, const float* __restrict__ gcn_b,
    float (*__restrict__ s_xc4)[4], float* __restrict__ s_xc1,
    float (*__restrict__ s_me4)[4], float* __restrict__ s_me1,
    uint_t* __restrict__ s_adj32,
    float (*__restrict__ s_xin)[NC], float (*__restrict__ s_xout)[NC])
{
    const float scale = 0.44721359549995793f; // 1/sqrt(5)
    const int n = tid >> 1, h = tid & 1;

    // stage mem (310 floats, 128 threads strided)
    for (int i = tid; i < NC * NB; i += 128) {
        const int c = i / NB, m = i - c * NB;
        if (c < 4) s_me4[m][c] = memp[i];
        else       s_me1[m]    = memp[i];
    }

    // ---- conv1x1: threads 0..61, node = tid ----
    if (tid < NB) {
        float cw[25], cbv[5];
        #pragma unroll
        for (int i = 0; i < 25; ++i) cw[i] = conv_w[i];
        #pragma unroll
        for (int i = 0; i < 5; ++i)  cbv[i] = conv_b[i];
        float xn[5];
        #pragma unroll
        for (int c = 0; c < 5; ++c)
            xn[c] = (L == 0) ? xin_g[c * NB + tid] : s_xin[tid][c];
        float xo[5];
        #pragma unroll
        for (int o = 0; o < 5; ++o) {
            float a = cbv[o];
            #pragma unroll
            for (int c = 0; c < 5; ++c) a = fmaf(cw[o * 5 + c], xn[c], a);
            xo[o] = a;
        }
        s_xc4[tid][0] = xo[0]; s_xc4[tid][1] = xo[1];
        s_xc4[tid][2] = xo[2]; s_xc4[tid][3] = xo[3];
        s_xc1[tid] = xo[4];
    }
    __syncthreads();

    // ---- row phase: pair (n,h) owns half-row m = h*31 .. h*31+30 ----
    if (n < NB) {
        const float w0 = gfc_w[0], w1 = gfc_w[1], b0 = gfc_b[0];
        const float4 xo03 = *(const float4*)&s_xc4[n][0];
        const float  xo4  = s_xc1[n];
        float r1[31], r2[31];
        #pragma unroll
        for (int i = 0; i < 31; ++i) {
            const int m = h * 31 + i;
            const float4 xc03 = *(const float4*)&s_xc4[m][0];
            const float  xc4  = s_xc1[m];
            const float4 me03 = *(const float4*)&s_me4[m][0];
            const float  me4  = s_me1[m];
            float s1 = xo03.x * me03.x + xo03.y * me03.y + xo03.z * me03.z +
                       xo03.w * me03.w + xo4 * me4;
            float s2 = xo03.x * xc03.x + xo03.y * xc03.y + xo03.z * xc03.z +
                       xo03.w * xc03.w + xo4 * xc4;
            r1[i] = fmaxf(s1 * scale, 0.0f);
            r2[i] = fmaxf(s2 * scale, 0.0f);
        }
        // softmax(r1), pair-combined
        float mx1 = tmax31(r1);
        mx1 = fmaxf(mx1, __shfl_xor(mx1, 1, 64));
        #pragma unroll
        for (int i = 0; i < 31; ++i) r1[i] = __expf(r1[i] - mx1);
        float sm1 = tsum31(r1);
        sm1 += __shfl_xor(sm1, 1, 64);
        const float inv1 = 1.0f / sm1;
        // softmax(r2)
        float mx2 = tmax31(r2);
        mx2 = fmaxf(mx2, __shfl_xor(mx2, 1, 64));
        #pragma unroll
        for (int i = 0; i < 31; ++i) r2[i] = __expf(r2[i] - mx2);
        float sm2 = tsum31(r2);
        sm2 += __shfl_xor(sm2, 1, 64);
        const float inv2 = 1.0f / sm2;
        // af = w0*a1 + w1*a2 + b0   (r2 dies here)
        #pragma unroll
        for (int i = 0; i < 31; ++i)
            r1[i] = b0 + (r1[i] * inv1) * w0 + (r2[i] * inv2) * w1;
        // softmax(af), normalized (ranking sees normalized values)
        float mxa = tmax31(r1);
        mxa = fmaxf(mxa, __shfl_xor(mxa, 1, 64));
        #pragma unroll
        for (int i = 0; i < 31; ++i) r1[i] = __expf(r1[i] - mxa);
        float sma = tsum31(r1);
        sma += __shfl_xor(sma, 1, 64);
        const float inva = 1.0f / sma;
        #pragma unroll
        for (int i = 0; i < 31; ++i) r1[i] *= inva;

        // ---- 14th-smallest of the 62 (=49th largest), exact:
        //      own low16 (2x sort16 + merge), exchange 16 w/ partner, merge ----
        float ga[16], gb[16];
        #pragma unroll
        for (int i = 0; i < 16; ++i) ga[i] = r1[i];
        sort16(ga);
        #pragma unroll
        for (int i = 0; i < 15; ++i) gb[i] = r1[16 + i];
        gb[15] = INFINITY;
        sort16(gb);
        merge_low16(ga, gb);
        #pragma unroll
        for (int i = 0; i < 16; ++i) gb[i] = __shfl_xor(ga[i], 1, 64);
        merge_low16(ga, gb);      // set property -> bitwise-same on both lanes
        const float vth = ga[13];

        // ---- tie-aware selection == jax.lax.top_k (lower index first) ----
        int g_own = 0, eq_own = 0;
        #pragma unroll
        for (int i = 0; i < 31; ++i) {
            g_own  += (r1[i] > vth);
            eq_own += (r1[i] == vth);
        }
        const int G = g_own + __shfl_xor(g_own, 1, 64);
        const int eq_other = __shfl_xor(eq_own, 1, 64);
        int eq = h ? eq_other : 0;   // global prefix start for this half

        uint_t pend = 0, myfirst = 0;
        #pragma unroll
        for (int i = 0; i < 31; ++i) {
            const bool e  = (r1[i] == vth);
            const bool ss = (r1[i] > vth) || (e && (G + eq) < KTOP);
            const uint_t hb = (uint_t)f2b(ss ? r1[i] : 0.0f);
            eq += e ? 1 : 0;
            if (h == 0) {
                if (i & 1) s_adj32[n * 31 + (i >> 1)] = pend | (hb << 16);
                else       pend = hb;              // i==30 leaves m30 in pend
            } else {
                if (i == 0)      myfirst = hb;     // m31
                else if (i & 1)  pend = hb;        // even m
                else             s_adj32[n * 31 + 15 + (i >> 1)] = pend | (hb << 16);
            }
        }
        // dword 15 spans the halves: h0 has m30 (pend), h1 has m31 (myfirst)
        const uint_t xch = (uint_t)__shfl_xor((int)(h ? myfirst : pend), 1, 64);
        if (h == 0) s_adj32[n * 31 + 15] = pend | (xch << 16);
    }
    __syncthreads();

    // ---- diffusion + gcn mix + skip: pair handles column m=n, split over nn ----
    if (n < NB) {
        const int m = n;
        const int dw = m >> 1;
        const uint_t sh = (m & 1) ? 16u : 0u;
        float y0 = 0, y1 = 0, y2 = 0, y3 = 0, y4 = 0;
        #pragma unroll 4
        for (int j = 0; j < 31; ++j) {
            const int nn = h * 31 + j;
            const uint_t w = s_adj32[nn * 31 + dw];
            const float a = bits2f((w >> sh) << 16);
            const float4 xv = *(const float4*)&s_xc4[nn][0];
            const float  xv4 = s_xc1[nn];
            y0 = fmaf(xv.x, a, y0); y1 = fmaf(xv.y, a, y1); y2 = fmaf(xv.z, a, y2);
            y3 = fmaf(xv.w, a, y3); y4 = fmaf(xv4, a, y4);
        }
        y0 += __shfl_xor(y0, 1, 64); y1 += __shfl_xor(y1, 1, 64);
        y2 += __shfl_xor(y2, 1, 64); y3 += __shfl_xor(y3, 1, 64);
        y4 += __shfl_xor(y4, 1, 64);
        if (h == 0) {
            float gwv[25], gbv[5];
            #pragma unroll
            for (int i = 0; i < 25; ++i) gwv[i] = gcn_w[i];
            #pragma unroll
            for (int i = 0; i < 5; ++i)  gbv[i] = gcn_b[i];
            #pragma unroll
            for (int o = 0; o < 5; ++o) {
                const float z = gbv[o] + gwv[o * 5 + 0] * y0 + gwv[o * 5 + 1] * y1 +
                                gwv[o * 5 + 2] * y2 + gwv[o * 5 + 3] * y3 + gwv[o * 5 + 4] * y4;
                const float fi = (L == 0) ? xin_g[o * NB + m] : s_xin[m][o];
                s_xout[m][o] = z + fi;
            }
        }
    }
    __syncthreads();
}

// 128 threads (2 waves). Pair-split rows: peak live ~80 regs -> no spills at
// any allocation >=96. waves_per_eu(2,3): budget 256, proven-safe heuristic
// range. LDS 12648 B -> 12 blocks/CU (24 waves).
__global__ void __launch_bounds__(128) __attribute__((amdgpu_waves_per_eu(2, 3)))
encoder_kernel(
    const float* __restrict__ g_x,
    const float* __restrict__ c0w, const float* __restrict__ c0b,
    const float* __restrict__ m0,  const float* __restrict__ f0w,
    const float* __restrict__ f0b, const float* __restrict__ g0w,
    const float* __restrict__ g0b,
    const float* __restrict__ c1w, const float* __restrict__ c1b,
    const float* __restrict__ m1,  const float* __restrict__ f1w,
    const float* __restrict__ f1b, const float* __restrict__ g1w,
    const float* __restrict__ g1b,
    const float* __restrict__ caw1, const float* __restrict__ caw2,
    const float* __restrict__ saw,  const float* __restrict__ sab,
    const float* __restrict__ fc1w, const float* __restrict__ fc1b,
    const float* __restrict__ fc2w, const float* __restrict__ fc2b,
    const ushort_t* __restrict__ w1b, const float* __restrict__ w2p,
    const int use_ws,
    float* __restrict__ g_out)
{
    const int b   = blockIdx.x;
    const int tid = threadIdx.x;

    // LDS: 992+248 + 992+248 + 7688 + 1240 + 1240 = 12648 B
    __shared__ __align__(16) float s_xc4[NB][4];
    __shared__ __align__(16) float s_xc1[NB];
    __shared__ __align__(16) float s_me4[NB][4];
    __shared__ __align__(16) float s_me1[NB];
    __shared__ __align__(16) uint_t s_adj32[NB * 31];
    __shared__ __align__(16) float s_x1[NB][NC];
    __shared__ __align__(16) float s_x2[NB][NC];

    float* const s_g  = (float*)s_adj32;          // 944 f32 alias (adj dead)
    float* const s_h1 = ((float*)s_adj32) + 944;  // 64 f32

    const float* xin = g_x + (size_t)b * (NC * NB);

    dgcn_layer<0>(tid, xin, c0w, c0b, m0, f0w, f0b, g0w, g0b,
                  s_xc4, s_xc1, s_me4, s_me1, s_adj32, nullptr, s_x1);
    dgcn_layer<1>(tid, xin, c1w, c1b, m1, f1w, f1b, g1w, g1b,
                  s_xc4, s_xc1, s_me4, s_me1, s_adj32, s_x1, s_x2);

    // ================= CBAM (wave 0 produces; all threads run shuffles) ======
    float f0[5], f1v[5], f2v[5];
    #pragma unroll
    for (int c = 0; c < 5; ++c) {
        f0[c]  = (tid < NB) ? xin[c * NB + tid] : 0.0f;
        f1v[c] = (tid < NB) ? s_x1[tid][c] : 0.0f;
        f2v[c] = (tid < NB) ? s_x2[tid][c] : 0.0f;
    }
    float mxp[15], avp[15];
    #pragma unroll
    for (int c = 0; c < 15; ++c) {
        const float v = (c < 5) ? f0[c] : (c < 10) ? f1v[c - 5] : f2v[c - 10];
        float vm = (tid < NB) ? v : -INFINITY;
        float vs = (tid < NB) ? v : 0.0f;
        #pragma unroll
        for (int off = 32; off > 0; off >>= 1) {
            vm = fmaxf(vm, __shfl_xor(vm, off, 64));
            vs += __shfl_xor(vs, off, 64);
        }
        mxp[c] = vm;
        avp[c] = vs * (1.0f / 62.0f);
    }
    float ca[15];
    {
        float hm[3], ha[3];
        #pragma unroll
        for (int o = 0; o < 3; ++o) {
            float am = 0.0f, aa = 0.0f;
            #pragma unroll
            for (int c = 0; c < 15; ++c) {
                const float w = caw1[o * 15 + c];
                am = fmaf(mxp[c], w, am);
                aa = fmaf(avp[c], w, aa);
            }
            hm[o] = fmaxf(am, 0.0f);
            ha[o] = fmaxf(aa, 0.0f);
        }
        #pragma unroll
        for (int c = 0; c < 15; ++c) {
            float t = 0.0f;
            #pragma unroll
            for (int o = 0; o < 3; ++o) t = fmaf(hm[o] + ha[o], caw2[c * 3 + o], t);
            ca[c] = sigmf(t);
        }
    }
    float og[15];
    float smx = -INFINITY, ssum = 0.0f;
    #pragma unroll
    for (int c = 0; c < 15; ++c) {
        const float fv = (c < 5) ? f0[c] : (c < 10) ? f1v[c - 5] : f2v[c - 10];
        const float v = fv * ca[c];
        og[c] = v;
        smx = fmaxf(smx, v);
        ssum += v;
    }
    const float smean = ssum * (1.0f / 15.0f);
    const float sxl = __shfl_up(smx, 1, 64),   sml = __shfl_up(smean, 1, 64);
    const float sxr = __shfl_down(smx, 1, 64), smr = __shfl_down(smean, 1, 64);
    const float mskL = (tid > 0) ? 1.0f : 0.0f;          // lane 0 of wave 0
    const float mskR = (tid < NB - 1) ? 1.0f : 0.0f;
    float t = sab[0];
    t += mskL * (sxl * saw[1] + sml * saw[10]);
    t += smx * saw[4] + smean * saw[13];
    t += mskR * (sxr * saw[7] + smr * saw[16]);
    const float sa = sigmf(t);

    __syncthreads();  // adjacency dead; region becomes s_g/s_h1
    if (tid < NB) {
        #pragma unroll
        for (int c = 0; c < 15; ++c) {
            const float fv = (c < 5) ? f0[c] : (c < 10) ? f1v[c - 5] : f2v[c - 10];
            s_g[c * NB + tid] = og[c] * sa + fv;
        }
    }
    if (tid < 14) s_g[930 + tid] = 0.0f;   // zero pad to 944
    __syncthreads();

    // ================= FC head (pair-split dots) =================
    const int o = tid >> 1, h = tid & 1;
    if (use_ws) {
        float acc = h ? 0.0f : fc1b[o];
        const uint4* w1v = (const uint4*)w1b;
        #pragma unroll 4
        for (int j = 0; j < 59; ++j) {
            const uint4 wv = w1v[j * 128 + tid];
            const int f = (h * 59 + j) * 8;
            const float4 ga4 = *(const float4*)&s_g[f];
            const float4 gb4 = *(const float4*)&s_g[f + 4];
            acc = fmaf(blo(wv.x), ga4.x, acc);
            acc = fmaf(bhi(wv.x), ga4.y, acc);
            acc = fmaf(blo(wv.y), ga4.z, acc);
            acc = fmaf(bhi(wv.y), ga4.w, acc);
            acc = fmaf(blo(wv.z), gb4.x, acc);
            acc = fmaf(bhi(wv.z), gb4.y, acc);
            acc = fmaf(blo(wv.w), gb4.z, acc);
            acc = fmaf(bhi(wv.w), gb4.w, acc);
        }
        acc += __shfl_xor(acc, 1, 64);
        if (h == 0) s_h1[o] = fmaxf(acc, 0.0f);
        __syncthreads();
        float acc2 = h ? 0.0f : fc2b[o];
        #pragma unroll
        for (int j = 0; j < 8; ++j) {
            const float4 wv = *(const float4*)(w2p + (j * 128 + tid) * 4);
            const float4 hv = *(const float4*)&s_h1[h * 32 + j * 4];
            acc2 = fmaf(wv.x, hv.x, acc2);
            acc2 = fmaf(wv.y, hv.y, acc2);
            acc2 = fmaf(wv.z, hv.z, acc2);
            acc2 = fmaf(wv.w, hv.w, acc2);
        }
        acc2 += __shfl_xor(acc2, 1, 64);
        if (h == 0) g_out[(size_t)b * 64 + o] = fmaxf(acc2, 0.0f);
    } else {
        // fallback: h==0 lane does the full (uncoalesced) dot
        float acc = 0.0f;
        if (h == 0) {
            acc = fc1b[o];
            const float* wr = fc1w + (size_t)o * 930;
            for (int i = 0; i < 930; i += 2)
                acc = fmaf(wr[i], s_g[i], fmaf(wr[i + 1], s_g[i + 1], acc));
        }
        acc += __shfl_xor(acc, 1, 64);
        if (h == 0) s_h1[o] = fmaxf(acc, 0.0f);
        __syncthreads();
        float acc2 = 0.0f;
        if (h == 0) {
            acc2 = fc2b[o];
            const float* wr2 = fc2w + o * 64;
            for (int k = 0; k < 64; ++k) acc2 = fmaf(wr2[k], s_h1[k], acc2);
            g_out[(size_t)b * 64 + o] = fmaxf(acc2, 0.0f);
        }
    }
}

extern "C" void kernel_launch(void* const* d_in, const int* in_sizes, int n_in,
                              void* d_out, int out_size, void* d_ws, size_t ws_size,
                              hipStream_t stream) {
    const float* X    = (const float*)d_in[0];
    const float* C0W  = (const float*)d_in[1];
    const float* C0B  = (const float*)d_in[2];
    const float* M0   = (const float*)d_in[3];
    const float* F0W  = (const float*)d_in[4];
    const float* F0B  = (const float*)d_in[5];
    const float* G0W  = (const float*)d_in[6];
    const float* G0B  = (const float*)d_in[7];
    const float* C1W  = (const float*)d_in[8];
    const float* C1B  = (const float*)d_in[9];
    const float* M1   = (const float*)d_in[10];
    const float* F1W  = (const float*)d_in[11];
    const float* F1B  = (const float*)d_in[12];
    const float* G1W  = (const float*)d_in[13];
    const float* G1B  = (const float*)d_in[14];
    const float* CAW1 = (const float*)d_in[15];
    const float* CAW2 = (const float*)d_in[16];
    const float* SAW  = (const float*)d_in[17];
    const float* SAB  = (const float*)d_in[18];
    const float* FC1W = (const float*)d_in[19];
    const float* FC1B = (const float*)d_in[20];
    const float* FC2W = (const float*)d_in[21];
    const float* FC2B = (const float*)d_in[22];

    const int B = in_sizes[0] / (NC * NB);

    const size_t W1_BYTES = 59 * 128 * 8 * sizeof(ushort_t); // 120832
    const size_t W2_BYTES = 8 * 128 * 4 * sizeof(float);     // 16384
    const int use_ws = (ws_size >= W1_BYTES + W2_BYTES) ? 1 : 0;
    ushort_t* w1b = (ushort_t*)d_ws;
    float*    w2p = (float*)((char*)d_ws + W1_BYTES);

    if (use_ws) {
        repack_kernel<<<252, 256, 0, stream>>>(FC1W, FC2W, w1b, w2p);
    }

    encoder_kernel<<<B, 128, 0, stream>>>(
        X, C0W, C0B, M0, F0W, F0B, G0W, G0B,
        C1W, C1B, M1, F1W, F1B, G1W, G1B,
        CAW1, CAW2, SAW, SAB, FC1W, FC1B, FC2W, FC2B,
        w1b, w2p, use_ws,
        (float*)d_out);
}